// Round 6
// baseline (533.330 us; speedup 1.0000x reference)
//
#include <hip/hip_runtime.h>
#include <hip/hip_bf16.h>
#include <hip/hip_cooperative_groups.h>

#define TOKEN_DIM 16
#define RANGES 5
#define MAX_RS 20000   // acc: 80,000 B LDS -> exactly 2 blocks/CU (phase2 overlays this)
#define MAX_C  96      // multiple of 8: every XCD owns exactly C/8 chunks
#define NXCD   8
#define P2G    16      // phase-2 C-split groups (1024 threads / 64 lanes)

typedef float floatx4 __attribute__((ext_vector_type(4)));

namespace cg = cooperative_groups;

// ---------------- phase 1 body (chunk c, range r scatter into LDS) ----------------
__device__ __forceinline__
void phase1_body(float* acc,
                 const int* __restrict__ row, const int* __restrict__ col,
                 const float* __restrict__ x, unsigned short* __restrict__ partial,
                 int N, long long E, int chunkE, int RS, int C, int b) {
    const int t = threadIdx.x, nt = blockDim.x;
    const int k = b % NXCD;                 // physical XCD (round-robin heuristic)
    const int s = b / NXCD;
    const int r = s % RANGES;
    const int c = k + NXCD * (s / RANGES);  // chunk: c % 8 == k (verified r1/r4: FETCH 126->27 MB)
    if (c >= C) return;                     // block-uniform skip; grid sync happens outside

    const int base = r * RS;
    int cnt = N - base; if (cnt > RS) cnt = RS; if (cnt < 0) cnt = 0;
    const unsigned ucnt = (unsigned)cnt;

    for (int j = t; j < cnt; j += nt) acc[j] = 0.0f;
    __syncthreads();

    long long i0 = (long long)c * chunkE;
    long long i1 = i0 + chunkE; if (i1 > E) i1 = E;
    long long len = (i1 > i0) ? (i1 - i0) : 0;
    long long ngrp = len >> 3;              // 8 edges/group (i0 is 8-aligned)

    long long g = t;
    int4 r0a, r1a, c0a, c1a;
    if (g < ngrp) {
        long long idx = i0 + (g << 3);
        r0a = *reinterpret_cast<const int4*>(row + idx);
        r1a = *reinterpret_cast<const int4*>(row + idx + 4);
        c0a = *reinterpret_cast<const int4*>(col + idx);
        c1a = *reinterpret_cast<const int4*>(col + idx + 4);
    }
    while (g < ngrp) {
        const unsigned d0 = (unsigned)(r0a.x - base);
        const unsigned d1 = (unsigned)(r0a.y - base);
        const unsigned d2 = (unsigned)(r0a.z - base);
        const unsigned d3 = (unsigned)(r0a.w - base);
        const unsigned d4 = (unsigned)(r1a.x - base);
        const unsigned d5 = (unsigned)(r1a.y - base);
        const unsigned d6 = (unsigned)(r1a.z - base);
        const unsigned d7 = (unsigned)(r1a.w - base);

        // 1) exec-masked gathers issued FIRST (oldest in vmcnt order)
        float v0, v1, v2, v3, v4, v5, v6, v7;
        if (d0 < ucnt) v0 = x[c0a.x];
        if (d1 < ucnt) v1 = x[c0a.y];
        if (d2 < ucnt) v2 = x[c0a.z];
        if (d3 < ucnt) v3 = x[c0a.w];
        if (d4 < ucnt) v4 = x[c1a.x];
        if (d5 < ucnt) v5 = x[c1a.y];
        if (d6 < ucnt) v6 = x[c1a.z];
        if (d7 < ucnt) v7 = x[c1a.w];

        // 2) THEN prefetch next index group: waiting for the gathers now only
        //    needs vmcnt(4) - the 4 index loads stay in flight across the
        //    atomic pass (was: prefetch first -> full vmcnt(0) drain per iter)
        const long long gn = g + nt;
        int4 r0b, r1b, c0b, c1b;
        if (gn < ngrp) {
            long long idx = i0 + (gn << 3);
            r0b = *reinterpret_cast<const int4*>(row + idx);
            r1b = *reinterpret_cast<const int4*>(row + idx + 4);
            c0b = *reinterpret_cast<const int4*>(col + idx);
            c1b = *reinterpret_cast<const int4*>(col + idx + 4);
        }
        __builtin_amdgcn_sched_barrier(0);  // pin: both load passes before the atomics

        // 3) exec-masked LDS atomics
        if (d0 < ucnt) atomicAdd(&acc[d0], v0);
        if (d1 < ucnt) atomicAdd(&acc[d1], v1);
        if (d2 < ucnt) atomicAdd(&acc[d2], v2);
        if (d3 < ucnt) atomicAdd(&acc[d3], v3);
        if (d4 < ucnt) atomicAdd(&acc[d4], v4);
        if (d5 < ucnt) atomicAdd(&acc[d5], v5);
        if (d6 < ucnt) atomicAdd(&acc[d6], v6);
        if (d7 < ucnt) atomicAdd(&acc[d7], v7);

        r0a = r0b; r1a = r1b; c0a = c0b; c1a = c1b;
        g = gn;
    }
    for (long long idx = i0 + (ngrp << 3) + t; idx < i1; idx += nt) {
        unsigned d = (unsigned)(row[idx] - base);
        if (d < ucnt) atomicAdd(&acc[d], x[col[idx]]);
    }
    __syncthreads();

    // paired bf16 writeback, plain stores (partial stays cached for phase 2)
    unsigned short* dst = partial + (size_t)c * N + base;    // 4B-aligned (N, base even)
    unsigned int* dst2 = reinterpret_cast<unsigned int*>(dst);
    const int cnt2 = cnt >> 1;
    for (int j = t; j < cnt2; j += nt) {
        __hip_bfloat16 ha = __float2bfloat16(acc[2 * j]);
        __hip_bfloat16 hb = __float2bfloat16(acc[2 * j + 1]);
        unsigned int w = (unsigned int)(*reinterpret_cast<unsigned short*>(&ha))
                       | ((unsigned int)(*reinterpret_cast<unsigned short*>(&hb)) << 16);
        dst2[j] = w;
    }
    if ((cnt & 1) && t == 0) {
        __hip_bfloat16 h = __float2bfloat16(acc[cnt - 1]);
        dst[cnt - 1] = *reinterpret_cast<unsigned short*>(&h);
    }
}

// ---------------- phase 2 body (reduce C partials + MLP), grid-stride tiles ----------------
__device__ __forceinline__
void phase2_body(float* lds,     // >= P2G*256 + 320 floats (overlays phase-1 acc)
                 const float* __restrict__ x, const unsigned short* __restrict__ partial,
                 const float* __restrict__ w1, const float* __restrict__ b1,
                 const float* __restrict__ w2, const float* __restrict__ b2,
                 float* __restrict__ out, int N, int C, int b, int gsz) {
    const int t = threadIdx.x;
    float* red  = lds;               // [P2G][256]
    float* wbuf = lds + P2G * 256;   // sw1[32] | sb1[16] | sw2[256] | sb2[16]
    if (t < 32) wbuf[t] = w1[t];
    else if (t < 48) wbuf[t] = b1[t - 32];
    else if (t < 304) wbuf[t] = w2[t - 48];
    else if (t < 320) wbuf[t] = b2[t - 304];

    const int lane = t & 63, grp = t >> 6;
    const int ntiles = (N + 255) >> 8;
    for (int tile = b; tile < ntiles; tile += gsz) {
        const int node0 = tile << 8;
        const int n4 = node0 + (lane << 2);
        float s0 = 0.f, s1 = 0.f, s2 = 0.f, s3 = 0.f;
        if (n4 + 3 < N) {
            const unsigned short* p = partial + n4;
            for (int cc = grp; cc < C; cc += P2G) {
                uint2 u = *reinterpret_cast<const uint2*>(p + (size_t)cc * N);  // 8B-aligned
                s0 += __uint_as_float(u.x << 16);
                s1 += __uint_as_float(u.x & 0xffff0000u);
                s2 += __uint_as_float(u.y << 16);
                s3 += __uint_as_float(u.y & 0xffff0000u);
            }
        } else if (n4 < N) {
            for (int cc = grp; cc < C; cc += P2G) {
                const unsigned short* p = partial + (size_t)cc * N;
                s0 += __uint_as_float(((unsigned)p[n4]) << 16);
                if (n4 + 1 < N) s1 += __uint_as_float(((unsigned)p[n4 + 1]) << 16);
                if (n4 + 2 < N) s2 += __uint_as_float(((unsigned)p[n4 + 2]) << 16);
            }
        }
        __syncthreads();   // previous tile's MLP reads done (and 1st-iter weight staging)
        floatx4 sv = { s0, s1, s2, s3 };
        *reinterpret_cast<floatx4*>(&red[grp * 256 + (lane << 2)]) = sv;
        __syncthreads();

        if (t < 256) {
            const int n = node0 + t;
            if (n < N) {
                float ssum = 0.f;
#pragma unroll
                for (int gi = 0; gi < P2G; ++gi) ssum += red[gi * 256 + t];
                const float xv = x[n];
                const float lv = xv * ssum;
                const float* sw1 = wbuf;
                const float* sb1 = wbuf + 32;
                const float* sw2 = wbuf + 48;
                const float* sb2 = wbuf + 304;

                float h[TOKEN_DIM];
#pragma unroll
                for (int j = 0; j < TOKEN_DIM; ++j) {
                    float v = fmaf(xv, sw1[2 * j], fmaf(lv, sw1[2 * j + 1], sb1[j]));
                    h[j] = v > 0.0f ? v : 0.0f;
                }
                floatx4* op = reinterpret_cast<floatx4*>(out + (size_t)n * TOKEN_DIM);
#pragma unroll
                for (int j4 = 0; j4 < 4; ++j4) {
                    floatx4 o;
#pragma unroll
                    for (int jj = 0; jj < 4; ++jj) {
                        const int j = j4 * 4 + jj;
                        float v = sb2[j];
#pragma unroll
                        for (int kk = 0; kk < TOKEN_DIM; ++kk)
                            v = fmaf(h[kk], sw2[j * TOKEN_DIM + kk], v);
                        o[jj] = v > 0.0f ? v : 0.0f;
                    }
                    op[j4] = o;
                }
            }
        }
    }
}

// ---------------- fused cooperative kernel ----------------
__global__ __launch_bounds__(1024, 8)
void nit_fused(const int* __restrict__ row, const int* __restrict__ col,
               const float* __restrict__ x, unsigned short* __restrict__ partial,
               const float* __restrict__ w1, const float* __restrict__ b1,
               const float* __restrict__ w2, const float* __restrict__ b2,
               float* __restrict__ out, int N, long long E, int chunkE, int RS, int C) {
    __shared__ float acc[MAX_RS];   // 80,000 B; phase2 overlays red(16KB)+weights(1.3KB)
    phase1_body(acc, row, col, x, partial, N, E, chunkE, RS, C, blockIdx.x);

    __threadfence();                // device-scope release: partial visible across XCDs
    cg::this_grid().sync();
    __threadfence();                // device-scope acquire: drop stale lines

    phase2_body(acc, x, partial, w1, b1, w2, b2, out, N, C, blockIdx.x, gridDim.x);
}

// ---------------- fallback path (two plain launches) ----------------
__global__ __launch_bounds__(1024, 8)
void nit_p1(const int* __restrict__ row, const int* __restrict__ col,
            const float* __restrict__ x, unsigned short* __restrict__ partial,
            int N, long long E, int chunkE, int RS, int C) {
    __shared__ float acc[MAX_RS];
    phase1_body(acc, row, col, x, partial, N, E, chunkE, RS, C, blockIdx.x);
}

__global__ __launch_bounds__(1024, 8)
void nit_p2(const float* __restrict__ x, const unsigned short* __restrict__ partial,
            const float* __restrict__ w1, const float* __restrict__ b1,
            const float* __restrict__ w2, const float* __restrict__ b2,
            float* __restrict__ out, int N, int C) {
    __shared__ float lds[P2G * 256 + 320];
    phase2_body(lds, x, partial, w1, b1, w2, b2, out, N, C, blockIdx.x, gridDim.x);
}

extern "C" void kernel_launch(void* const* d_in, const int* in_sizes, int n_in,
                              void* d_out, int out_size, void* d_ws, size_t ws_size,
                              hipStream_t stream) {
    const int*   ei = (const int*)d_in[1];   // [2, E] flat: rows then cols
    const float* x  = (const float*)d_in[0];
    const float* w1 = (const float*)d_in[2];
    const float* b1 = (const float*)d_in[3];
    const float* w2 = (const float*)d_in[4];
    const float* b2 = (const float*)d_in[5];
    float* out = (float*)d_out;

    int N = in_sizes[0];
    long long E = in_sizes[1] / 2;
    const int* row = ei;
    const int* col = ei + E;

    long long maxC = (long long)(ws_size / ((size_t)N * sizeof(unsigned short)));
    int C = maxC < 1 ? 1 : (maxC > MAX_C ? MAX_C : (int)maxC);
    int RS = ((N + RANGES - 1) / RANGES + 1) & ~1;   // even -> 4B-aligned bf16 slices
    long long ce = (E + C - 1) / C;
    int chunkE = (int)((ce + 7LL) & ~7LL);           // 8-aligned for int4 group loads

    unsigned short* partial = (unsigned short*)d_ws;

    const int cgc = (C + NXCD - 1) / NXCD;
    int grid1 = NXCD * RANGES * cgc;                 // 480 for C=96 (= co-residency cap)

    void* args[] = { (void*)&row, (void*)&col, (void*)&x, (void*)&partial,
                     (void*)&w1, (void*)&b1, (void*)&w2, (void*)&b2, (void*)&out,
                     (void*)&N, (void*)&E, (void*)&chunkE, (void*)&RS, (void*)&C };
    hipError_t err = hipLaunchCooperativeKernel((const void*)nit_fused,
                                                dim3(grid1), dim3(1024),
                                                args, 0, stream);
    if (err != hipSuccess) {
        // fallback: plain two-kernel path (round-5 behavior)
        nit_p1<<<grid1, 1024, 0, stream>>>(row, col, x, partial, N, E, chunkE, RS, C);
        nit_p2<<<grid1, 1024, 0, stream>>>(x, partial, w1, b1, w2, b2, out, N, C);
    }
}

// Round 7
// 141.251 us; speedup vs baseline: 3.7758x; 3.7758x over previous
//
#include <hip/hip_runtime.h>
#include <hip/hip_bf16.h>

#define TOKEN_DIM 16
#define RANGES 3       // was 5: LDS 133KB/block, 1 block/CU -> scan work 5E -> 3E
                       // (TA is per-CU; 2 co-resident blocks never doubled it)
#define MAX_C  80      // grid = 3*C = 240; per XCD: 30 blocks <= 32 CUs (no 2x tail)
#define NXCD   8

typedef float floatx4 __attribute__((ext_vector_type(4)));

// Phase 1: block (chunk c, range r) scans edge chunk c, accumulates
// s[row] += x[col] for rows in its range via LDS atomics (exec-masked),
// writes its partial slice (bf16) non-atomically.
// XCD co-location (verified r1/r4: FETCH 126 MB -> 27 MB): c % 8 == blockIdx % 8.
__global__ __launch_bounds__(1024, 4)
void nit_phase1(const int* __restrict__ row, const int* __restrict__ col,
                const float* __restrict__ x,
                unsigned short* __restrict__ partial,   // [C][N] bf16 bits
                int N, long long E, int chunkE, int RS, int C) {
    extern __shared__ float acc[];          // RS floats (133,336 B for RS=33334)
    const int b = blockIdx.x;
    const int k = b % NXCD;                 // physical XCD (round-robin heuristic)
    const int s = b / NXCD;
    const int r = s % RANGES;
    const int c = k + NXCD * (s / RANGES);  // chunk: c % 8 == k
    if (c >= C) return;                     // block-uniform, before any barrier

    const int base = r * RS;
    int cnt = N - base; if (cnt > RS) cnt = RS; if (cnt < 0) cnt = 0;
    const int t = threadIdx.x, nt = blockDim.x;
    const unsigned ucnt = (unsigned)cnt;

    for (int j = t; j < cnt; j += nt) acc[j] = 0.0f;
    __syncthreads();

    long long i0 = (long long)c * chunkE;
    long long i1 = i0 + chunkE; if (i1 > E) i1 = E;
    long long len = (i1 > i0) ? (i1 - i0) : 0;
    long long ngrp = len >> 3;              // 8 edges/group (i0 is 8-aligned)

    long long g = t;
    int4 r0a, r1a, c0a, c1a;
    if (g < ngrp) {
        long long idx = i0 + (g << 3);
        r0a = *reinterpret_cast<const int4*>(row + idx);
        r1a = *reinterpret_cast<const int4*>(row + idx + 4);
        c0a = *reinterpret_cast<const int4*>(col + idx);
        c1a = *reinterpret_cast<const int4*>(col + idx + 4);
    }
    while (g < ngrp) {
        const unsigned d0 = (unsigned)(r0a.x - base);
        const unsigned d1 = (unsigned)(r0a.y - base);
        const unsigned d2 = (unsigned)(r0a.z - base);
        const unsigned d3 = (unsigned)(r0a.w - base);
        const unsigned d4 = (unsigned)(r1a.x - base);
        const unsigned d5 = (unsigned)(r1a.y - base);
        const unsigned d6 = (unsigned)(r1a.z - base);
        const unsigned d7 = (unsigned)(r1a.w - base);

        // 1) exec-masked gathers issued first (oldest in vmcnt order)
        float v0, v1, v2, v3, v4, v5, v6, v7;
        if (d0 < ucnt) v0 = x[c0a.x];
        if (d1 < ucnt) v1 = x[c0a.y];
        if (d2 < ucnt) v2 = x[c0a.z];
        if (d3 < ucnt) v3 = x[c0a.w];
        if (d4 < ucnt) v4 = x[c1a.x];
        if (d5 < ucnt) v5 = x[c1a.y];
        if (d6 < ucnt) v6 = x[c1a.z];
        if (d7 < ucnt) v7 = x[c1a.w];

        // 2) then prefetch next index group (stays in flight across atomics)
        const long long gn = g + nt;
        int4 r0b, r1b, c0b, c1b;
        if (gn < ngrp) {
            long long idx = i0 + (gn << 3);
            r0b = *reinterpret_cast<const int4*>(row + idx);
            r1b = *reinterpret_cast<const int4*>(row + idx + 4);
            c0b = *reinterpret_cast<const int4*>(col + idx);
            c1b = *reinterpret_cast<const int4*>(col + idx + 4);
        }
        __builtin_amdgcn_sched_barrier(0);

        // 3) exec-masked LDS atomics
        if (d0 < ucnt) atomicAdd(&acc[d0], v0);
        if (d1 < ucnt) atomicAdd(&acc[d1], v1);
        if (d2 < ucnt) atomicAdd(&acc[d2], v2);
        if (d3 < ucnt) atomicAdd(&acc[d3], v3);
        if (d4 < ucnt) atomicAdd(&acc[d4], v4);
        if (d5 < ucnt) atomicAdd(&acc[d5], v5);
        if (d6 < ucnt) atomicAdd(&acc[d6], v6);
        if (d7 < ucnt) atomicAdd(&acc[d7], v7);

        r0a = r0b; r1a = r1b; c0a = c0b; c1a = c1b;
        g = gn;
    }
    for (long long idx = i0 + (ngrp << 3) + t; idx < i1; idx += nt) {
        unsigned d = (unsigned)(row[idx] - base);
        if (d < ucnt) atomicAdd(&acc[d], x[col[idx]]);
    }
    __syncthreads();

    // paired bf16 writeback, plain stores (partial stays cached for phase 2)
    unsigned short* dst = partial + (size_t)c * N + base;    // 4B-aligned (N, base even)
    unsigned int* dst2 = reinterpret_cast<unsigned int*>(dst);
    const int cnt2 = cnt >> 1;
    for (int j = t; j < cnt2; j += nt) {
        __hip_bfloat16 ha = __float2bfloat16(acc[2 * j]);
        __hip_bfloat16 hb = __float2bfloat16(acc[2 * j + 1]);
        unsigned int w = (unsigned int)(*reinterpret_cast<unsigned short*>(&ha))
                       | ((unsigned int)(*reinterpret_cast<unsigned short*>(&hb)) << 16);
        dst2[j] = w;
    }
    if ((cnt & 1) && t == 0) {
        __hip_bfloat16 h = __float2bfloat16(acc[cnt - 1]);
        dst[cnt - 1] = *reinterpret_cast<unsigned short*>(&h);
    }
}

// Phase 2 (unchanged from r5, ~<10 us): 256 nodes/block, uint2 (4 bf16) reads,
// C split across 4 wave-groups, LDS reduce, all 256 threads run the MLP.
__global__ __launch_bounds__(256, 8)
void nit_phase2(const float* __restrict__ x,
                const unsigned short* __restrict__ partial,
                const float* __restrict__ w1, const float* __restrict__ b1,
                const float* __restrict__ w2, const float* __restrict__ b2,
                float* __restrict__ out, int N, int C) {
    __shared__ float sw1[TOKEN_DIM * 2];
    __shared__ float sb1[TOKEN_DIM];
    __shared__ float sw2[TOKEN_DIM * TOKEN_DIM];
    __shared__ float sb2[TOKEN_DIM];
    __shared__ float red[4][256];

    const int t = threadIdx.x;
    sw2[t] = w2[t];
    if (t < TOKEN_DIM * 2) sw1[t] = w1[t];
    if (t < TOKEN_DIM) { sb1[t] = b1[t]; sb2[t] = b2[t]; }

    const int lane = t & 63;
    const int grp  = t >> 6;
    const int node0 = blockIdx.x << 8;
    const int n4 = node0 + (lane << 2);

    float s0 = 0.0f, s1 = 0.0f, s2 = 0.0f, s3 = 0.0f;
    if (n4 + 3 < N) {
        const unsigned short* p = partial + n4;
#pragma unroll 4
        for (int c = grp; c < C; c += 4) {
            uint2 u = *reinterpret_cast<const uint2*>(p + (size_t)c * N);  // 8B-aligned
            s0 += __uint_as_float(u.x << 16);
            s1 += __uint_as_float(u.x & 0xffff0000u);
            s2 += __uint_as_float(u.y << 16);
            s3 += __uint_as_float(u.y & 0xffff0000u);
        }
    } else if (n4 < N) {
        for (int c = grp; c < C; c += 4) {
            const unsigned short* p = partial + (size_t)c * N;
            s0 += __uint_as_float(((unsigned)p[n4]) << 16);
            if (n4 + 1 < N) s1 += __uint_as_float(((unsigned)p[n4 + 1]) << 16);
            if (n4 + 2 < N) s2 += __uint_as_float(((unsigned)p[n4 + 2]) << 16);
        }
    }
    floatx4 sv = { s0, s1, s2, s3 };
    *reinterpret_cast<floatx4*>(&red[grp][lane << 2]) = sv;
    __syncthreads();

    const int n = node0 + t;
    if (n < N) {
        const float ssum = red[0][t] + red[1][t] + red[2][t] + red[3][t];
        const float xv = x[n];
        const float lv = xv * ssum;

        float h[TOKEN_DIM];
#pragma unroll
        for (int j = 0; j < TOKEN_DIM; ++j) {
            float v = fmaf(xv, sw1[2 * j], fmaf(lv, sw1[2 * j + 1], sb1[j]));
            h[j] = v > 0.0f ? v : 0.0f;
        }

        float o[TOKEN_DIM];
#pragma unroll
        for (int j = 0; j < TOKEN_DIM; ++j) {
            float v = sb2[j];
#pragma unroll
            for (int kk = 0; kk < TOKEN_DIM; ++kk)
                v = fmaf(h[kk], sw2[j * TOKEN_DIM + kk], v);
            o[j] = v > 0.0f ? v : 0.0f;
        }

        floatx4* op = reinterpret_cast<floatx4*>(out + (size_t)n * TOKEN_DIM);
#pragma unroll
        for (int j = 0; j < 4; ++j) {
            floatx4 w = { o[4 * j], o[4 * j + 1], o[4 * j + 2], o[4 * j + 3] };
            op[j] = w;
        }
    }
}

extern "C" void kernel_launch(void* const* d_in, const int* in_sizes, int n_in,
                              void* d_out, int out_size, void* d_ws, size_t ws_size,
                              hipStream_t stream) {
    const float* x  = (const float*)d_in[0];
    const int*   ei = (const int*)d_in[1];   // [2, E] flat: rows then cols
    const float* w1 = (const float*)d_in[2];
    const float* b1 = (const float*)d_in[3];
    const float* w2 = (const float*)d_in[4];
    const float* b2 = (const float*)d_in[5];
    float* out = (float*)d_out;

    const int N = in_sizes[0];
    const long long E = in_sizes[1] / 2;
    const int* row = ei;
    const int* col = ei + E;

    long long maxC = (long long)(ws_size / ((size_t)N * sizeof(unsigned short)));
    int C = maxC < 1 ? 1 : (maxC > MAX_C ? MAX_C : (int)maxC);
    int RS = ((N + RANGES - 1) / RANGES + 1) & ~1;   // 33334: even -> 4B-aligned slices
    long long ce = (E + C - 1) / C;
    int chunkE = (int)((ce + 7LL) & ~7LL);           // 8-aligned for int4 group loads

    unsigned short* partial = (unsigned short*)d_ws;
    const size_t ldsBytes = (size_t)RS * sizeof(float);   // 133,336 B

    // opt in to >64KB dynamic LDS (once per process; host-side, capture-safe)
    static bool attrSet = false;
    if (!attrSet) {
        (void)hipFuncSetAttribute((const void*)nit_phase1,
                                  hipFuncAttributeMaxDynamicSharedMemorySize,
                                  (int)ldsBytes);
        attrSet = true;
    }

    const int cgc = (C + NXCD - 1) / NXCD;           // 10 for C=80
    const int grid1 = NXCD * RANGES * cgc;           // 240: 30 blocks/XCD <= 32 CUs
    nit_phase1<<<grid1, 1024, ldsBytes, stream>>>(row, col, x, partial,
                                                  N, E, chunkE, RS, C);

    int grid2 = (N + 255) / 256;
    nit_phase2<<<grid2, 256, 0, stream>>>(x, partial, w1, b1, w2, b2,
                                          out, N, C);
}